// Round 1
// baseline (239.339 us; speedup 1.0000x reference)
//
#include <hip/hip_runtime.h>

#define NB 32
#define NC 128
#define NH 56
#define NW 56
#define HP 58
#define WP 58
#define KK 1152
#define NPOS 3136                         // 56*56
#define XT_BYTES (NB * HP * WP * NC * 2)  // 27,557,888
#define AW_OFF XT_BYTES

typedef __attribute__((ext_vector_type(8))) short s16x8;
typedef __attribute__((ext_vector_type(4))) float f32x4;
typedef unsigned int u32;

__device__ __forceinline__ unsigned short f2bf(float f) {
    union { float f; unsigned int u; } v; v.f = f;
    unsigned int u = v.u + 0x7fffu + ((v.u >> 16) & 1u);
    return (unsigned short)(u >> 16);
}

__device__ __forceinline__ void gld16(const void* g, void* l) {
    __builtin_amdgcn_global_load_lds(
        (const __attribute__((address_space(1))) u32*)g,
        (__attribute__((address_space(3))) u32*)l, 16, 0, 0);
}

// ---- fused prologue v2: register-only, no LDS, no syncthreads ----
// blocks [0,7168):    xpose  x [B,C,56,56]f32 -> xt [B,58,58,C]bf16 interior
//                     thread = (b, y, cgi, xp): 8 channel-strided gathers
//                     (lane-coalesced: 56 lanes read 224B contiguous/instr),
//                     one 16B store. Every x byte fetched exactly once.
// blocks [7168,7456): wperm  w -> aw MFMA lane-order, 8 elems/thread:
//                     aw[t*8+j] = bf16(w[(m*128+icb+j)*9+g]); dest linear 16B.
// blocks [7456,7912): halo   zero rows y'=0,57 (full) + cols x'=0,57.
#define XPB 7168
#define WPB 7456
#define PROGRID 7912

__global__ void k_pro(const float* __restrict__ x, const float* __restrict__ w,
                      unsigned short* __restrict__ xt, unsigned short* __restrict__ aw) {
    int blk = blockIdx.x;
    int tid = threadIdx.x;
    if (blk < XPB) {
        int t = blk * 256 + tid;
        int xp = t & 63;                    // lane = x position (56 active)
        int unit = t >> 6;                  // (b*56+y)*16 + cgi
        int cgi = unit & 15;
        int by = unit >> 4;
        int y = by % 56, b = by / 56;
        if (xp < 56) {
            const float* xs = x + ((size_t)(b * 128 + cgi * 8) * NPOS) + y * 56 + xp;
            s16x8 v;
#pragma unroll
            for (int j = 0; j < 8; ++j)
                v[j] = (short)f2bf(xs[(size_t)j * NPOS]);
            *(s16x8*)(xt + (((size_t)(b * HP + y + 1) * WP) + (xp + 1)) * NC + cgi * 8) = v;
        }
        return;
    }
    if (blk < WPB) {
        int t = (blk - XPB) * 256 + tid;    // [0, 73728)
        int lane = t & 63;
        int mt = (t >> 6) & 31;
        int s = t >> 11;                    // [0, 36)
        int m = mt * 16 + (lane & 15);
        int kgb = s * 32 + (lane >> 4) * 8;
        int g = kgb >> 7, icb = kgb & 127;
        const float* ws = w + ((size_t)m * 128 + icb) * 9 + g;
        s16x8 v;
#pragma unroll
        for (int j = 0; j < 8; ++j)
            v[j] = (short)f2bf(ws[j * 9]);
        *(s16x8*)(aw + (size_t)t * 8) = v;
        return;
    }
    // halo zero: 116736 x 16B stores, exact grid fit
    int h = (blk - WPB) * 256 + tid;
    s16x8 z = {};
    if (h < 59392) {                        // top/bottom rows: 1856 stores per b
        int b = h / 1856, r = h - b * 1856;
        int row = (r < 928) ? 0 : 57;
        int i = (r < 928) ? r : r - 928;    // [0,928) over 7424 shorts
        *(s16x8*)(xt + ((size_t)(b * HP + row) * WP * NC) + i * 8) = z;
    } else {                                // side cols: (b,y,side) x 16 stores
        int h2 = h - 59392;                 // [0, 57344)
        int i = h2 & 15, rest = h2 >> 4;
        int side = rest & 1; rest >>= 1;    // rest = b*56+y
        int y = rest % 56, b = rest / 56;
        int xcol = side ? 57 : 0;
        *(s16x8*)(xt + (((size_t)(b * HP + y + 1) * WP) + xcol) * NC + i * 8) = z;
    }
}

// ---- main: fused implicit-GEMM conv + softmax rank combine + biases ----
// (UNCHANGED this round — attribution: k_main's own rocprof row must stay ~132us)
// 8 waves, M=512 (4 ranks x 128 ch), N=112 (2 image rows), K=1152.
// 9 barrier-stages of K=128 = one 3x3 filter tap each. A: global->VGPR
// ping-pong. B: shared LDS 2x28KB dbuf via gld16, XOR-16 chunk swizzle.
// PHASE STAGGER: odd waves process the 4 K32 sub-slices rotated by 2, so the
// two waves on each SIMD anti-align their ds_read bursts vs MFMA bursts.
__global__ void __launch_bounds__(512, 2) k_main(
    const unsigned short* __restrict__ xt, const unsigned short* __restrict__ aw,
    const float* __restrict__ cwr, const float* __restrict__ cwc,
    const float* __restrict__ brow, const float* __restrict__ bcol,
    const float* __restrict__ bch, float* __restrict__ out) {
    __shared__ __align__(16) unsigned char ldsB[2][28672];   // 112 rows x 256B

    const int tid = threadIdx.x;
    const int lane = tid & 63;
    const int wv = tid >> 6;
    const int l15 = lane & 15, quad = lane >> 4;
    const int ph = (wv & 1) * 2;            // per-parity sub-slice rotation
    const int blk = blockIdx.x;
    const int b = blk / 28;
    const int tile0 = (blk - b * 28) * 112;

    const unsigned char* xt_b = (const unsigned char*)xt + (size_t)b * (HP * WP * NC * 2);
    const unsigned char* gA = (const unsigned char*)aw + wv * 1024 + lane * 16;

    // B staging: wave wv (0..6) stages rows wv*16..+15; gld16 #h covers 4 rows
    // (h*4 + lane>>4), phys chunk lane&15, global chunk (lane&15)^(row&15).
    const unsigned char* gB[4];
    if (wv < 7) {
#pragma unroll
        for (int h = 0; h < 4; ++h) {
            int rl = h * 4 + (lane >> 4);
            int row = wv * 16 + rl;
            int pos = tile0 + row;
            int yy = pos / 56, xx = pos - yy * 56;
            int c = (lane & 15) ^ rl;
            gB[h] = xt_b + ((yy + 1) * WP + (xx + 1)) * (NC * 2) + c * 16;
        }
    }

    s16x8 Areg[2][4];          // [pingpong][rank]
    f32x4 acc[4][7] = {};      // [rank][ntile]

    auto aload = [&](int s32, int pp) {
#pragma unroll
        for (int r = 0; r < 4; ++r)
            Areg[pp][r] = *(const s16x8*)(gA + s32 * 32768 + r * 8192);
    };
    auto bissue = [&](int st, int buf) {
        if (wv < 7) {
            int dy = (st * 11) >> 5, dx = st - dy * 3;
            int off = ((dy - 1) * WP + (dx - 1)) * (NC * 2);
            unsigned char* L = &ldsB[buf][wv * 4096];
#pragma unroll
            for (int h = 0; h < 4; ++h) gld16(gB[h] + off, L + h * 1024);
        }
    };

    aload(ph, 0);              // first slice in this wave's rotated sequence
    bissue(0, 0);
    __syncthreads();

    for (int st = 0; st < 9; ++st) {
        const int cur = st & 1;
        if (st < 8) bissue(st + 1, cur ^ 1);
        const unsigned char* L = &ldsB[cur][0];
#pragma unroll
        for (int j = 0; j < 4; ++j) {
            const int kkw = (j + ph) & 3;      // this wave's sub-slice this beat
            // prefetch next slice in this wave's own sequence
            if (!(st == 8 && j == 3)) {
                int nslice = (j < 3) ? st * 4 + (((j + 1) + ph) & 3)
                                     : (st + 1) * 4 + ph;
                aload(nslice, (j + 1) & 1);
            }
            s16x8 bf[7];
#pragma unroll
            for (int t = 0; t < 7; ++t)
                bf[t] = *(const s16x8*)(L + (t * 16 + l15) * 256
                                          + (((kkw * 4 + quad) ^ l15) << 4));
#pragma unroll
            for (int r = 0; r < 4; ++r)
#pragma unroll
                for (int t = 0; t < 7; ++t)
                    acc[r][t] = __builtin_amdgcn_mfma_f32_16x16x32_bf16(
                        Areg[j & 1][r], bf[t], acc[r][t], 0, 0, 0);
        }
        __syncthreads();
    }

    // epilogue: inline softmax over rank + combine + biases, fp32 store
#pragma unroll
    for (int t = 0; t < 7; ++t) {
        int pos = tile0 + t * 16 + l15;
        int yy = pos / 56, xx = pos - yy * 56;
        float v0 = cwr[yy]       + cwc[xx];
        float v1 = cwr[56 + yy]  + cwc[56 + xx];
        float v2 = cwr[112 + yy] + cwc[112 + xx];
        float v3 = cwr[168 + yy] + cwc[168 + xx];
        float mx = fmaxf(fmaxf(v0, v1), fmaxf(v2, v3));
        float e0 = __expf(v0 - mx), e1 = __expf(v1 - mx);
        float e2 = __expf(v2 - mx), e3 = __expf(v3 - mx);
        float inv = 1.0f / (e0 + e1 + e2 + e3);
        float c0 = e0 * inv, c1 = e1 * inv, c2 = e2 * inv, c3 = e3 * inv;
        float rb = brow[yy] + bcol[xx];
#pragma unroll
        for (int r = 0; r < 4; ++r) {
            int ch = wv * 16 + quad * 4 + r;
            float v = acc[0][t][r] * c0 + acc[1][t][r] * c1
                    + acc[2][t][r] * c2 + acc[3][t][r] * c3;
            out[((size_t)b * NC + ch) * NPOS + pos] = v + bch[ch] + rb;
        }
    }
}

extern "C" void kernel_launch(void* const* d_in, const int* in_sizes, int n_in,
                              void* d_out, int out_size, void* d_ws, size_t ws_size,
                              hipStream_t stream) {
    const float* x    = (const float*)d_in[0];
    const float* w    = (const float*)d_in[1];
    const float* cwr  = (const float*)d_in[2];
    const float* cwc  = (const float*)d_in[3];
    const float* brow = (const float*)d_in[4];
    const float* bcol = (const float*)d_in[5];
    const float* bch  = (const float*)d_in[6];
    float* out = (float*)d_out;

    unsigned char* ws = (unsigned char*)d_ws;
    unsigned short* xt = (unsigned short*)ws;
    unsigned short* aw = (unsigned short*)(ws + AW_OFF);

    k_pro<<<PROGRID, 256, 0, stream>>>(x, w, xt, aw);   // xpose + wperm + halo
    k_main<<<NB * 28, 512, 0, stream>>>(xt, aw, cwr, cwc, brow, bcol, bch, out);
}